// Round 5
// baseline (5119.160 us; speedup 1.0000x reference)
//
#include <hip/hip_runtime.h>

#define Bb 512
#define Tt 256
#define Ee 256
#define Uu 512
#define Vv 10000

// d_out staging layout (bytes). d_out = 512*10000*4 = 20,480,000 B (fp32 out).
// packB  @ 0           6,291,456  bf16 MFMA-packed [Wx;Wh], both dirs
// hbuf   @ 6,291,456   2,097,152  bf16 [parity][dir][B][U] ping-pong
// cbuf   @ 8,388,608   2,097,152  fp32 [dir][B][U] cell state
// hidden @10,485,760     131,072  fp32 [512][64]  -> ends 10,616,832
// Final fp32 softmax write covers all 20,480,000 B; hidden region overlaps
// only out rows 262..265, handled by the single-block tail pass.
#define PACKB_OFF 0
#define HBUF_OFF  6291456
#define CBUF_OFF  8388608
#define HID_OFF   10485760

typedef __attribute__((ext_vector_type(8))) short short8;
typedef __attribute__((ext_vector_type(4))) float f32x4;

__device__ __forceinline__ float bf2f(ushort u) {
  union { unsigned int i; float f; } v; v.i = ((unsigned int)u) << 16; return v.f;
}
__device__ __forceinline__ ushort f2bf(float f) {
  union { float f; unsigned int i; } v; v.f = f;
  unsigned int x = v.i;
  return (ushort)((x + 0x7fffu + ((x >> 16) & 1u)) >> 16);  // RNE, finite inputs
}
__device__ __forceinline__ float fast_sigmoid(float x) {
  return 1.f / (1.f + __expf(-x));
}
__device__ __forceinline__ float fast_tanh(float x) {
  float t = __expf(-2.f * fabsf(x));
  float r = (1.f - t) / (1.f + t);
  return x >= 0.f ? r : -r;
}

// ---------------------------------------------------------------------------
// Zero hbuf (both parities, bf16) + cbuf (fp32): 4,194,304 B from HBUF_OFF.
// grid 1024 x 256 threads x 16 B.
// ---------------------------------------------------------------------------
__global__ __launch_bounds__(256) void init_zero(char* ob)
{
  uint4 z; z.x = 0; z.y = 0; z.z = 0; z.w = 0;
  ((uint4*)(ob + HBUF_OFF))[(size_t)blockIdx.x * 256 + threadIdx.x] = z;
}

// ---------------------------------------------------------------------------
// Pack W = concat(Wx[E][2048], Wh[U][2048]) (fp32) per dir into bf16 MFMA
// B-fragments:
// packB[((d*128 + ct)*24 + ks)*512 + lane*8 + j] =
//     bf16( W[k = ks*32 + (lane>>4)*8 + j][col = ct*16 + (lane&15)] )
// grid (4, 24, 2), block 256.
// ---------------------------------------------------------------------------
__global__ __launch_bounds__(256) void pack_weights(
    const float* __restrict__ Wx_fw, const float* __restrict__ Wh_fw,
    const float* __restrict__ Wx_bw, const float* __restrict__ Wh_bw,
    char* ob)
{
  __shared__ ushort tile[32][520];  // +8 pad breaks bank aliasing
  ushort* packB = (ushort*)(ob + PACKB_OFF);
  const int cq = blockIdx.x;   // 0..3 (512 cols each)
  const int ks = blockIdx.y;   // 0..23
  const int d  = blockIdx.z;   // 0..1
  const int tid = threadIdx.x;
  const float* Wx = d ? Wx_bw : Wx_fw;
  const float* Wh = d ? Wh_bw : Wh_fw;
  const int colbase = cq * 512;

  #pragma unroll
  for (int i = 0; i < 8; i++) {
    int chunk = tid + i * 256;        // 0..2047
    int row = chunk >> 6;             // 0..31
    int cc = (chunk & 63) * 8;        // 0..504
    int k = ks * 32 + row;
    const float* src = (k < Ee) ? (Wx + (size_t)k * 2048 + colbase + cc)
                                : (Wh + (size_t)(k - Ee) * 2048 + colbase + cc);
    f32x4 f0 = *(const f32x4*)src;
    f32x4 f1 = *(const f32x4*)(src + 4);
    #pragma unroll
    for (int j = 0; j < 4; j++) {
      tile[row][cc + j]     = f2bf(f0[j]);
      tile[row][cc + 4 + j] = f2bf(f1[j]);
    }
  }
  __syncthreads();
  #pragma unroll
  for (int i = 0; i < 8; i++) {
    int chunk = tid + i * 256;
    int ctl = chunk >> 6;             // 0..31 local col-tile
    int lane = chunk & 63;
    int quad = lane >> 4, l15 = lane & 15;
    short8 v;
    #pragma unroll
    for (int jj = 0; jj < 8; jj++)
      v[jj] = (short)tile[quad * 8 + jj][ctl * 16 + l15];
    int ct = (colbase >> 4) + ctl;    // global col-tile 0..127
    *(short8*)(packB + (((size_t)(d * 128 + ct) * 24 + ks) * 512) + lane * 8) = v;
  }
}

// ---------------------------------------------------------------------------
// One LSTM timestep, both dirs. Block = [64 batch x 32 u] gate quadruple:
// G[64, 4*32] = [x_t, h] @ [Wx;Wh] + b via 16x16x32 bf16 MFMA (K=768),
// then the pointwise c/h update locally. c fp32, h bf16 ping-pong.
// grid (16, 8, 2), block 256 (wave w = M-tile w).
// ---------------------------------------------------------------------------
__global__ __launch_bounds__(256) void lstm_step(
    char* ob,
    const int*   __restrict__ sent,   // [B][T] int32
    const float* __restrict__ emb,    // [V][E] fp32
    const float* __restrict__ b_fw,   // [4U] fp32
    const float* __restrict__ b_bw,
    int s)
{
  const ushort* packB = (const ushort*)(ob + PACKB_OFF);
  ushort* hbuf = (ushort*)(ob + HBUF_OFF);
  float*  cbuf = (float*)(ob + CBUF_OFF);

  const int ut = blockIdx.x;  // u-tile: u0 = ut*32
  const int bt = blockIdx.y;  // b-tile: b0 = bt*64
  const int d  = blockIdx.z;
  const int tid = threadIdx.x;
  const int w = tid >> 6;
  const int lane = tid & 63;
  const int l15 = lane & 15, quad = lane >> 4;
  const int b0 = bt * 64;
  const int t = d ? (Tt - 1 - s) : s;

  const int mrow = b0 + w * 16 + l15;      // A-operand row (m = lane&15)
  const int tok = sent[mrow * Tt + t];

  const ushort* hread  = hbuf + (size_t)((s & 1) * 2 + d) * Bb * Uu;
  ushort*       hwrite = hbuf + (size_t)((((s & 1) ^ 1) * 2) + d) * Bb * Uu;

  const float*  aemb = emb + (size_t)tok * Ee + quad * 8;
  const ushort* ah   = hread + (size_t)mrow * Uu + quad * 8;

  const ushort* bbase[2][4];
  #pragma unroll
  for (int j = 0; j < 2; j++)
    #pragma unroll
    for (int q = 0; q < 4; q++)
      bbase[j][q] = packB + ((size_t)(d * 128 + q * 32 + ut * 2 + j) * 24) * 512 + lane * 8;

  f32x4 acc[2][4];
  #pragma unroll
  for (int j = 0; j < 2; j++)
    #pragma unroll
    for (int q = 0; q < 4; q++)
      acc[j][q] = (f32x4){0.f, 0.f, 0.f, 0.f};

  // K part 1: embedding (ks = 0..7), fp32 -> bf16 A-fragment
  #pragma unroll
  for (int ks = 0; ks < 8; ks++) {
    f32x4 f0 = *(const f32x4*)(aemb + ks * 32);
    f32x4 f1 = *(const f32x4*)(aemb + ks * 32 + 4);
    short8 a;
    #pragma unroll
    for (int j = 0; j < 4; j++) {
      a[j]     = (short)f2bf(f0[j]);
      a[4 + j] = (short)f2bf(f1[j]);
    }
    #pragma unroll
    for (int j = 0; j < 2; j++)
      #pragma unroll
      for (int q = 0; q < 4; q++) {
        short8 bv = *(const short8*)(bbase[j][q] + ks * 512);
        acc[j][q] = __builtin_amdgcn_mfma_f32_16x16x32_bf16(a, bv, acc[j][q], 0, 0, 0);
      }
  }
  // K part 2: recurrent h (ks = 8..23), h already bf16
  #pragma unroll
  for (int ks = 8; ks < 24; ks++) {
    short8 a = *(const short8*)(ah + (ks - 8) * 32);
    #pragma unroll
    for (int j = 0; j < 2; j++)
      #pragma unroll
      for (int q = 0; q < 4; q++) {
        short8 bv = *(const short8*)(bbase[j][q] + ks * 512);
        acc[j][q] = __builtin_amdgcn_mfma_f32_16x16x32_bf16(a, bv, acc[j][q], 0, 0, 0);
      }
  }

  // Pointwise. C/D layout: col = lane&15 (u), row = quad*4 + reg (batch).
  const float* bias = d ? b_bw : b_fw;
  #pragma unroll
  for (int j = 0; j < 2; j++) {
    int u = ut * 32 + j * 16 + l15;
    float bi  = bias[u];
    float bff = bias[512 + u];
    float bg  = bias[1024 + u];
    float bo  = bias[1536 + u];
    #pragma unroll
    for (int r = 0; r < 4; r++) {
      int m = b0 + w * 16 + quad * 4 + r;
      float iv = fast_sigmoid(acc[j][0][r] + bi);
      float fv = fast_sigmoid(acc[j][1][r] + bff);
      float gv = fast_tanh(acc[j][2][r] + bg);
      float ov = fast_sigmoid(acc[j][3][r] + bo);
      size_t cidx = ((size_t)d * Bb + m) * Uu + u;
      float cn = fv * cbuf[cidx] + iv * gv;
      cbuf[cidx] = cn;
      hwrite[(size_t)m * Uu + u] = f2bf(ov * fast_tanh(cn));
    }
  }
}

// ---------------------------------------------------------------------------
// hidden = relu([h_fw, h_bw] @ W1 + b1) -> fp32 @ HID_OFF.
// grid 128, block 256: 4 rows x 64 cols per block.
// ---------------------------------------------------------------------------
__global__ __launch_bounds__(256) void hidden_kernel(
    char* ob, const float* __restrict__ W1, const float* __restrict__ b1)
{
  const ushort* hbuf = (const ushort*)(ob + HBUF_OFF);   // parity 0 = final h
  float* hidden = (float*)(ob + HID_OFF);
  int m = blockIdx.x * 4 + (threadIdx.x >> 6);
  int col = threadIdx.x & 63;
  const ushort* hf = hbuf + (size_t)m * Uu;              // dir 0
  const ushort* hb = hbuf + (size_t)(Bb + m) * Uu;       // dir 1
  float acc = b1[col];
  for (int k = 0; k < 512; k++) acc += bf2f(hf[k]) * W1[k * 64 + col];
  for (int k = 0; k < 512; k++) acc += bf2f(hb[k]) * W1[(512 + k) * 64 + col];
  hidden[(size_t)m * 64 + col] = fmaxf(acc, 0.f);
}

// ---------------------------------------------------------------------------
// Softmax row body: given hs[64] in LDS, compute + store fp32 probs for row m.
// ---------------------------------------------------------------------------
__device__ __forceinline__ void softmax_row(
    const float* hs, const float* __restrict__ W2, const float* __restrict__ b2,
    float* out, int m, float* red)
{
  const int tid = threadIdx.x;
  float lg[40];
  float mx = -1e30f;
  #pragma unroll 4
  for (int i = 0; i < 40; i++) {
    int c = tid + i * 256;
    float a = -1e30f;
    if (c < Vv) {
      a = b2[c];
      for (int k = 0; k < 64; k++) a += hs[k] * W2[(size_t)k * Vv + c];
    }
    lg[i] = a;
    mx = fmaxf(mx, a);
  }
  red[tid] = mx; __syncthreads();
  for (int off = 128; off > 0; off >>= 1) {
    if (tid < off) red[tid] = fmaxf(red[tid], red[tid + off]);
    __syncthreads();
  }
  mx = red[0];
  __syncthreads();

  float sum = 0.f;
  #pragma unroll 4
  for (int i = 0; i < 40; i++) {
    int c = tid + i * 256;
    if (c < Vv) { lg[i] = __expf(lg[i] - mx); sum += lg[i]; }
  }
  red[tid] = sum; __syncthreads();
  for (int off = 128; off > 0; off >>= 1) {
    if (tid < off) red[tid] += red[tid + off];
    __syncthreads();
  }
  float inv = 1.f / red[0];
  __syncthreads();
  #pragma unroll 4
  for (int i = 0; i < 40; i++) {
    int c = tid + i * 256;
    if (c < Vv) out[(size_t)m * Vv + c] = lg[i] * inv;
  }
}

// ---------------------------------------------------------------------------
// Pass A: rows {0..261} u {266..511} — write ranges provably disjoint from the
// hidden region (rows 262..265 are the only overlap). grid 508.
// ---------------------------------------------------------------------------
__global__ __launch_bounds__(256) void logits_main(
    char* ob, const float* __restrict__ W2, const float* __restrict__ b2)
{
  __shared__ float hs[64];
  __shared__ float red[256];
  const float* hidden = (const float*)(ob + HID_OFF);
  float* out = (float*)ob;
  int bx = blockIdx.x;
  int m = (bx < 262) ? bx : (bx + 4);
  if (threadIdx.x < 64) hs[threadIdx.x] = hidden[(size_t)m * 64 + threadIdx.x];
  __syncthreads();
  softmax_row(hs, W2, b2, out, m, red);
}

// ---------------------------------------------------------------------------
// Pass B: rows 262..265, ONE block. Preload all 4 hidden rows into LDS before
// any store (row 263's write range contains all 4 hidden rows).
// ---------------------------------------------------------------------------
__global__ __launch_bounds__(256) void logits_tail(
    char* ob, const float* __restrict__ W2, const float* __restrict__ b2)
{
  __shared__ float hs4[4][64];
  __shared__ float red[256];
  const float* hidden = (const float*)(ob + HID_OFF);
  float* out = (float*)ob;
  if (threadIdx.x < 256) {
    int r = threadIdx.x >> 6, col = threadIdx.x & 63;
    hs4[r][col] = hidden[(size_t)(262 + r) * 64 + col];
  }
  __syncthreads();   // all hidden reads complete before any store
  for (int r = 0; r < 4; r++) {
    softmax_row(hs4[r], W2, b2, out, 262 + r, red);
    __syncthreads();
  }
}

extern "C" void kernel_launch(void* const* d_in, const int* in_sizes, int n_in,
                              void* d_out, int out_size, void* d_ws, size_t ws_size,
                              hipStream_t stream)
{
  const int*   sent  = (const int*)d_in[0];
  const float* emb   = (const float*)d_in[1];
  const float* Wx_fw = (const float*)d_in[2];
  const float* Wh_fw = (const float*)d_in[3];
  const float* b_fw  = (const float*)d_in[4];
  const float* Wx_bw = (const float*)d_in[5];
  const float* Wh_bw = (const float*)d_in[6];
  const float* b_bw  = (const float*)d_in[7];
  const float* W1    = (const float*)d_in[8];
  const float* b1    = (const float*)d_in[9];
  const float* W2    = (const float*)d_in[10];
  const float* b2    = (const float*)d_in[11];
  char* ob = (char*)d_out;
  (void)d_ws; (void)ws_size; (void)in_sizes; (void)n_in; (void)out_size;

  init_zero<<<1024, 256, 0, stream>>>(ob);
  pack_weights<<<dim3(4, 24, 2), 256, 0, stream>>>(Wx_fw, Wh_fw, Wx_bw, Wh_bw, ob);

  for (int s = 0; s < Tt; s++)
    lstm_step<<<dim3(16, 8, 2), 256, 0, stream>>>(ob, sent, emb, b_fw, b_bw, s);

  hidden_kernel<<<128, 256, 0, stream>>>(ob, W1, b1);

  logits_main<<<508, 256, 0, stream>>>(ob, W2, b2);
  logits_tail<<<1,   256, 0, stream>>>(ob, W2, b2);
}

// Round 6
// 4250.917 us; speedup vs baseline: 1.2042x; 1.2042x over previous
//
#include <hip/hip_runtime.h>

#define Bb 512
#define Tt 256
#define Ee 256
#define Uu 512
#define Vv 10000

// d_out staging layout (bytes). d_out = 512*10000*4 = 20,480,000 B (fp32 out).
// packB  @ 0           6,291,456  bf16 MFMA-packed [Wx;Wh], both dirs
// hbuf   @ 6,291,456   2,097,152  bf16 [parity][dir][B][U] ping-pong
// hidden @ 8,388,608     131,072  fp32 [512][64]
// cnt    @ 8,519,680       1,024  8 group counters, 128 B apart
// embB   @12,582,912   5,120,000  bf16 emb table
// Final fp32 softmax write covers everything; `hidden` overlaps only out rows
// 209..212 -> handled by the single-block tail pass. cnt/packB/hbuf/embB are
// dead by then.
#define PACKB_OFF 0
#define HBUF_OFF  6291456
#define HID_OFF   8388608
#define CNT_OFF   8519680
#define EMB_OFF   12582912

typedef __attribute__((ext_vector_type(8))) short short8;
typedef __attribute__((ext_vector_type(4))) float f32x4;

__device__ __forceinline__ float bf2f(ushort u) {
  union { unsigned int i; float f; } v; v.i = ((unsigned int)u) << 16; return v.f;
}
__device__ __forceinline__ ushort f2bf(float f) {
  union { float f; unsigned int i; } v; v.f = f;
  unsigned int x = v.i;
  return (ushort)((x + 0x7fffu + ((x >> 16) & 1u)) >> 16);  // RNE
}
__device__ __forceinline__ float fast_sigmoid(float x) {
  return 1.f / (1.f + __expf(-x));
}
__device__ __forceinline__ float fast_tanh(float x) {
  float t = __expf(-2.f * fabsf(x));
  float r = (1.f - t) / (1.f + t);
  return x >= 0.f ? r : -r;
}

// Coherent (L2-bypassing, device-scope) h accessors: h is the only buffer
// mutated cross-block during the persistent kernel, so no fences/invalidates
// are needed anywhere — emb/packB stay L2-warm.
__device__ __forceinline__ short8 load_h16(const ushort* p) {
  union { unsigned long long u[2]; short8 s; } v;
  v.u[0] = __hip_atomic_load((const unsigned long long*)p,     __ATOMIC_RELAXED, __HIP_MEMORY_SCOPE_AGENT);
  v.u[1] = __hip_atomic_load((const unsigned long long*)p + 1, __ATOMIC_RELAXED, __HIP_MEMORY_SCOPE_AGENT);
  return v.s;
}
__device__ __forceinline__ void store_h(ushort* p, ushort v) {
  __hip_atomic_store(p, v, __ATOMIC_RELAXED, __HIP_MEMORY_SCOPE_AGENT);
}

// ---------------------------------------------------------------------------
// Zero hbuf (2 MB) + group counters (1 KB). 513 blocks.
// ---------------------------------------------------------------------------
__global__ __launch_bounds__(256) void init_zero(char* ob)
{
  if (blockIdx.x < 512) {
    uint4 z; z.x = 0; z.y = 0; z.z = 0; z.w = 0;
    ((uint4*)(ob + HBUF_OFF))[(size_t)blockIdx.x * 256 + threadIdx.x] = z;
  } else {
    ((unsigned int*)(ob + CNT_OFF))[threadIdx.x] = 0u;
  }
}

// ---------------------------------------------------------------------------
// emb fp32 -> bf16 table. 1250 blocks x 256 thr x 8 elems = 2,560,000.
// ---------------------------------------------------------------------------
__global__ __launch_bounds__(256) void conv_emb(const float* __restrict__ emb, char* ob)
{
  ushort* embB = (ushort*)(ob + EMB_OFF);
  size_t i = ((size_t)blockIdx.x * 256 + threadIdx.x) * 8;
  f32x4 f0 = *(const f32x4*)(emb + i);
  f32x4 f1 = *(const f32x4*)(emb + i + 4);
  short8 v;
  #pragma unroll
  for (int j = 0; j < 4; j++) {
    v[j]     = (short)f2bf(f0[j]);
    v[4 + j] = (short)f2bf(f1[j]);
  }
  *(short8*)(embB + i) = v;
}

// ---------------------------------------------------------------------------
// Pack W = concat(Wx[E][2048], Wh[U][2048]) (fp32) per dir into bf16 MFMA
// B-fragments: packB[((d*128 + ct)*24 + ks)*512 + lane*8 + j] =
//     bf16( W[k = ks*32 + (lane>>4)*8 + j][col = ct*16 + (lane&15)] )
// grid (4, 24, 2), block 256.
// ---------------------------------------------------------------------------
__global__ __launch_bounds__(256) void pack_weights(
    const float* __restrict__ Wx_fw, const float* __restrict__ Wh_fw,
    const float* __restrict__ Wx_bw, const float* __restrict__ Wh_bw,
    char* ob)
{
  __shared__ ushort tile[32][520];
  ushort* packB = (ushort*)(ob + PACKB_OFF);
  const int cq = blockIdx.x;
  const int ks = blockIdx.y;
  const int d  = blockIdx.z;
  const int tid = threadIdx.x;
  const float* Wx = d ? Wx_bw : Wx_fw;
  const float* Wh = d ? Wh_bw : Wh_fw;
  const int colbase = cq * 512;

  #pragma unroll
  for (int i = 0; i < 8; i++) {
    int chunk = tid + i * 256;
    int row = chunk >> 6;
    int cc = (chunk & 63) * 8;
    int k = ks * 32 + row;
    const float* src = (k < Ee) ? (Wx + (size_t)k * 2048 + colbase + cc)
                                : (Wh + (size_t)(k - Ee) * 2048 + colbase + cc);
    f32x4 f0 = *(const f32x4*)src;
    f32x4 f1 = *(const f32x4*)(src + 4);
    #pragma unroll
    for (int j = 0; j < 4; j++) {
      tile[row][cc + j]     = f2bf(f0[j]);
      tile[row][cc + 4 + j] = f2bf(f1[j]);
    }
  }
  __syncthreads();
  #pragma unroll
  for (int i = 0; i < 8; i++) {
    int chunk = tid + i * 256;
    int ctl = chunk >> 6;
    int lane = chunk & 63;
    int quad = lane >> 4, l15 = lane & 15;
    short8 v;
    #pragma unroll
    for (int jj = 0; jj < 8; jj++)
      v[jj] = (short)tile[quad * 8 + jj][ctl * 16 + l15];
    int ct = (colbase >> 4) + ctl;
    *(short8*)(packB + (((size_t)(d * 128 + ct) * 24 + ks) * 512) + lane * 8) = v;
  }
}

// ---------------------------------------------------------------------------
// Persistent bidirectional LSTM: all 256 steps in one launch.
// grid (32 utp, 4 bt, 2 d) = 256 blocks x 256 thr (4 waves).
// Block tile: [128 batch x 16 u] x 4 gates. Wave: 32 rows x 64 cols
// (2 M-tiles x 4 gates) -> B frags reused x2, A frags reused x4.
// Recurrent-part B (ks 8..23) lives in LDS (64 KB) for the whole kernel.
// c state in registers (8 floats/lane). h ping-pongs via coherent stores.
// Sync: per-(bt,d) group of 32 blocks, monotonic counter @CNT_OFF.
// ---------------------------------------------------------------------------
__global__ __launch_bounds__(256) void lstm_persistent(
    char* ob, const int* __restrict__ sent,
    const float* __restrict__ b_fw, const float* __restrict__ b_bw)
{
  __shared__ ushort ldsB[32768];   // 64 KB = [k8 0..15][q 0..3][512]
  const ushort* packB = (const ushort*)(ob + PACKB_OFF);
  const ushort* embB  = (const ushort*)(ob + EMB_OFF);
  ushort* hbuf = (ushort*)(ob + HBUF_OFF);

  const int utp = blockIdx.x;       // u-slice 0..31 (16 u each)
  const int bt  = blockIdx.y;       // batch slice 0..3 (128 rows)
  const int d   = blockIdx.z;
  unsigned int* cnt = (unsigned int*)(ob + CNT_OFF) + (d * 4 + bt) * 32;

  const int tid = threadIdx.x;
  const int w = tid >> 6, lane = tid & 63;
  const int l15 = lane & 15, quad = lane >> 4;
  const int mbase = bt * 128 + w * 32;
  const int u = utp * 16 + l15;

  // Stage recurrent-part B into LDS (once).
  for (int i = 0; i < 16; i++) {
    int c = tid + i * 256;                  // 0..4095 chunks of 16 B
    int lc = c & 63, qc = (c >> 6) & 3, k8 = c >> 8;
    const ushort* src = packB +
        ((size_t)(d * 128 + qc * 32 + utp) * 24 + 8 + k8) * 512 + lc * 8;
    *(short8*)&ldsB[(k8 * 4 + qc) * 512 + lc * 8] = *(const short8*)src;
  }

  const float* bias = d ? b_bw : b_fw;
  const float bi  = bias[u];
  const float bfv = bias[512 + u];
  const float bg  = bias[1024 + u];
  const float bo  = bias[1536 + u];

  const ushort* bembP[4];
  #pragma unroll
  for (int q = 0; q < 4; q++)
    bembP[q] = packB + ((size_t)(d * 128 + q * 32 + utp) * 24) * 512 + lane * 8;

  float creg[2][4];
  #pragma unroll
  for (int a = 0; a < 2; a++)
    #pragma unroll
    for (int r = 0; r < 4; r++) creg[a][r] = 0.f;

  __syncthreads();   // LDS B ready

  for (int s = 0; s < Tt; s++) {
    const int t = d ? (Tt - 1 - s) : s;
    const ushort* hread  = hbuf + (size_t)((s & 1) * 2 + d) * Bb * Uu;
    ushort*       hwrite = hbuf + (size_t)((((s & 1) ^ 1) * 2) + d) * Bb * Uu;

    f32x4 acc[2][4];
    #pragma unroll
    for (int a = 0; a < 2; a++)
      #pragma unroll
      for (int q = 0; q < 4; q++)
        acc[a][q] = (f32x4){0.f, 0.f, 0.f, 0.f};

    const int tok0 = sent[(mbase + l15) * Tt + t];
    const int tok1 = sent[(mbase + 16 + l15) * Tt + t];
    const ushort* e0 = embB + (size_t)tok0 * Ee + quad * 8;
    const ushort* e1 = embB + (size_t)tok1 * Ee + quad * 8;

    // ---- emb part (K 0..255): independent of peers -> before the wait ----
    #pragma unroll
    for (int ks = 0; ks < 8; ks++) {
      short8 bq0 = *(const short8*)(bembP[0] + ks * 512);
      short8 bq1 = *(const short8*)(bembP[1] + ks * 512);
      short8 bq2 = *(const short8*)(bembP[2] + ks * 512);
      short8 bq3 = *(const short8*)(bembP[3] + ks * 512);
      short8 a0 = *(const short8*)(e0 + ks * 32);
      short8 a1 = *(const short8*)(e1 + ks * 32);
      acc[0][0] = __builtin_amdgcn_mfma_f32_16x16x32_bf16(a0, bq0, acc[0][0], 0, 0, 0);
      acc[0][1] = __builtin_amdgcn_mfma_f32_16x16x32_bf16(a0, bq1, acc[0][1], 0, 0, 0);
      acc[0][2] = __builtin_amdgcn_mfma_f32_16x16x32_bf16(a0, bq2, acc[0][2], 0, 0, 0);
      acc[0][3] = __builtin_amdgcn_mfma_f32_16x16x32_bf16(a0, bq3, acc[0][3], 0, 0, 0);
      acc[1][0] = __builtin_amdgcn_mfma_f32_16x16x32_bf16(a1, bq0, acc[1][0], 0, 0, 0);
      acc[1][1] = __builtin_amdgcn_mfma_f32_16x16x32_bf16(a1, bq1, acc[1][1], 0, 0, 0);
      acc[1][2] = __builtin_amdgcn_mfma_f32_16x16x32_bf16(a1, bq2, acc[1][2], 0, 0, 0);
      acc[1][3] = __builtin_amdgcn_mfma_f32_16x16x32_bf16(a1, bq3, acc[1][3], 0, 0, 0);
    }

    // ---- wait: all 32 peer blocks finished step s-1 (h parity s&1 ready) --
    if (tid == 0) {
      const unsigned int target = 32u * (unsigned int)s;
      while (__hip_atomic_fetch_add(cnt, 0u, __ATOMIC_RELAXED,
                                    __HIP_MEMORY_SCOPE_AGENT) < target)
        __builtin_amdgcn_s_sleep(2);
    }
    __syncthreads();

    // ---- recurrent part (K 256..767): B from LDS, A via coherent loads ---
    const ushort* h0 = hread + (size_t)(mbase + l15) * Uu + quad * 8;
    const ushort* h1 = hread + (size_t)(mbase + 16 + l15) * Uu + quad * 8;
    #pragma unroll
    for (int k8 = 0; k8 < 16; k8++) {
      short8 bq0 = *(const short8*)&ldsB[(k8 * 4 + 0) * 512 + lane * 8];
      short8 bq1 = *(const short8*)&ldsB[(k8 * 4 + 1) * 512 + lane * 8];
      short8 bq2 = *(const short8*)&ldsB[(k8 * 4 + 2) * 512 + lane * 8];
      short8 bq3 = *(const short8*)&ldsB[(k8 * 4 + 3) * 512 + lane * 8];
      short8 a0 = load_h16(h0 + k8 * 32);
      short8 a1 = load_h16(h1 + k8 * 32);
      acc[0][0] = __builtin_amdgcn_mfma_f32_16x16x32_bf16(a0, bq0, acc[0][0], 0, 0, 0);
      acc[0][1] = __builtin_amdgcn_mfma_f32_16x16x32_bf16(a0, bq1, acc[0][1], 0, 0, 0);
      acc[0][2] = __builtin_amdgcn_mfma_f32_16x16x32_bf16(a0, bq2, acc[0][2], 0, 0, 0);
      acc[0][3] = __builtin_amdgcn_mfma_f32_16x16x32_bf16(a0, bq3, acc[0][3], 0, 0, 0);
      acc[1][0] = __builtin_amdgcn_mfma_f32_16x16x32_bf16(a1, bq0, acc[1][0], 0, 0, 0);
      acc[1][1] = __builtin_amdgcn_mfma_f32_16x16x32_bf16(a1, bq1, acc[1][1], 0, 0, 0);
      acc[1][2] = __builtin_amdgcn_mfma_f32_16x16x32_bf16(a1, bq2, acc[1][2], 0, 0, 0);
      acc[1][3] = __builtin_amdgcn_mfma_f32_16x16x32_bf16(a1, bq3, acc[1][3], 0, 0, 0);
    }

    // ---- pointwise: gates lane-local, c in regs, h out via coherent store -
    #pragma unroll
    for (int a = 0; a < 2; a++) {
      #pragma unroll
      for (int r = 0; r < 4; r++) {
        float iv = fast_sigmoid(acc[a][0][r] + bi);
        float fv = fast_sigmoid(acc[a][1][r] + bfv);
        float gv = fast_tanh(acc[a][2][r] + bg);
        float ov = fast_sigmoid(acc[a][3][r] + bo);
        float cn = fv * creg[a][r] + iv * gv;
        creg[a][r] = cn;
        int m = mbase + a * 16 + quad * 4 + r;
        store_h(hwrite + (size_t)m * Uu + u, f2bf(ov * fast_tanh(cn)));
      }
    }

    // ---- arrive: syncthreads drains vmcnt(0) in every thread first --------
    __syncthreads();
    if (tid == 0)
      __hip_atomic_fetch_add(cnt, 1u, __ATOMIC_RELAXED, __HIP_MEMORY_SCOPE_AGENT);
  }
}

// ---------------------------------------------------------------------------
// hidden = relu([h_fw, h_bw] @ W1 + b1) -> fp32 @ HID_OFF.
// grid 128, block 256: 4 rows x 64 cols.
// ---------------------------------------------------------------------------
__global__ __launch_bounds__(256) void hidden_kernel(
    char* ob, const float* __restrict__ W1, const float* __restrict__ b1)
{
  const ushort* hbuf = (const ushort*)(ob + HBUF_OFF);   // parity 0 = final h
  float* hidden = (float*)(ob + HID_OFF);
  int m = blockIdx.x * 4 + (threadIdx.x >> 6);
  int col = threadIdx.x & 63;
  const ushort* hf = hbuf + (size_t)m * Uu;
  const ushort* hb = hbuf + (size_t)(Bb + m) * Uu;
  float acc = b1[col];
  for (int k = 0; k < 512; k++) acc += bf2f(hf[k]) * W1[k * 64 + col];
  for (int k = 0; k < 512; k++) acc += bf2f(hb[k]) * W1[(512 + k) * 64 + col];
  hidden[(size_t)m * 64 + col] = fmaxf(acc, 0.f);
}

// ---------------------------------------------------------------------------
// Softmax row body: given hs[64] in LDS, compute + store fp32 probs for row m.
// ---------------------------------------------------------------------------
__device__ __forceinline__ void softmax_row(
    const float* hs, const float* __restrict__ W2, const float* __restrict__ b2,
    float* out, int m, float* red)
{
  const int tid = threadIdx.x;
  float lg[40];
  float mx = -1e30f;
  #pragma unroll 4
  for (int i = 0; i < 40; i++) {
    int c = tid + i * 256;
    float a = -1e30f;
    if (c < Vv) {
      a = b2[c];
      for (int k = 0; k < 64; k++) a += hs[k] * W2[(size_t)k * Vv + c];
    }
    lg[i] = a;
    mx = fmaxf(mx, a);
  }
  red[tid] = mx; __syncthreads();
  for (int off = 128; off > 0; off >>= 1) {
    if (tid < off) red[tid] = fmaxf(red[tid], red[tid + off]);
    __syncthreads();
  }
  mx = red[0];
  __syncthreads();

  float sum = 0.f;
  #pragma unroll 4
  for (int i = 0; i < 40; i++) {
    int c = tid + i * 256;
    if (c < Vv) { lg[i] = __expf(lg[i] - mx); sum += lg[i]; }
  }
  red[tid] = sum; __syncthreads();
  for (int off = 128; off > 0; off >>= 1) {
    if (tid < off) red[tid] += red[tid + off];
    __syncthreads();
  }
  float inv = 1.f / red[0];
  __syncthreads();
  #pragma unroll 4
  for (int i = 0; i < 40; i++) {
    int c = tid + i * 256;
    if (c < Vv) out[(size_t)m * Vv + c] = lg[i] * inv;
  }
}

// ---------------------------------------------------------------------------
// Pass A: all rows except 209..212 (those overlap the hidden staging region).
// ---------------------------------------------------------------------------
__global__ __launch_bounds__(256) void logits_main(
    char* ob, const float* __restrict__ W2, const float* __restrict__ b2)
{
  __shared__ float hs[64];
  __shared__ float red[256];
  const float* hidden = (const float*)(ob + HID_OFF);
  float* out = (float*)ob;
  int bx = blockIdx.x;
  int m = (bx < 209) ? bx : (bx + 4);
  if (threadIdx.x < 64) hs[threadIdx.x] = hidden[(size_t)m * 64 + threadIdx.x];
  __syncthreads();
  softmax_row(hs, W2, b2, out, m, red);
}

// ---------------------------------------------------------------------------
// Pass B: rows 209..212, ONE block; preload all 4 hidden rows before storing.
// ---------------------------------------------------------------------------
__global__ __launch_bounds__(256) void logits_tail(
    char* ob, const float* __restrict__ W2, const float* __restrict__ b2)
{
  __shared__ float hs4[4][64];
  __shared__ float red[256];
  const float* hidden = (const float*)(ob + HID_OFF);
  float* out = (float*)ob;
  {
    int r = threadIdx.x >> 6, col = threadIdx.x & 63;
    hs4[r][col] = hidden[(size_t)(209 + r) * 64 + col];
  }
  __syncthreads();
  for (int r = 0; r < 4; r++) {
    softmax_row(hs4[r], W2, b2, out, 209 + r, red);
    __syncthreads();
  }
}

extern "C" void kernel_launch(void* const* d_in, const int* in_sizes, int n_in,
                              void* d_out, int out_size, void* d_ws, size_t ws_size,
                              hipStream_t stream)
{
  const int*   sent  = (const int*)d_in[0];
  const float* emb   = (const float*)d_in[1];
  const float* Wx_fw = (const float*)d_in[2];
  const float* Wh_fw = (const float*)d_in[3];
  const float* b_fw  = (const float*)d_in[4];
  const float* Wx_bw = (const float*)d_in[5];
  const float* Wh_bw = (const float*)d_in[6];
  const float* b_bw  = (const float*)d_in[7];
  const float* W1    = (const float*)d_in[8];
  const float* b1    = (const float*)d_in[9];
  const float* W2    = (const float*)d_in[10];
  const float* b2    = (const float*)d_in[11];
  char* ob = (char*)d_out;
  (void)d_ws; (void)ws_size; (void)in_sizes; (void)n_in; (void)out_size;

  init_zero<<<513, 256, 0, stream>>>(ob);
  pack_weights<<<dim3(4, 24, 2), 256, 0, stream>>>(Wx_fw, Wh_fw, Wx_bw, Wh_bw, ob);
  conv_emb<<<1250, 256, 0, stream>>>(emb, ob);

  lstm_persistent<<<dim3(32, 4, 2), 256, 0, stream>>>(ob, sent, b_fw, b_bw);

  hidden_kernel<<<128, 256, 0, stream>>>(ob, W1, b1);
  logits_main<<<508, 256, 0, stream>>>(ob, W2, b2);
  logits_tail<<<1,   256, 0, stream>>>(ob, W2, b2);
}

// Round 7
// 4187.962 us; speedup vs baseline: 1.2224x; 1.0150x over previous
//
#include <hip/hip_runtime.h>

#define Bb 512
#define Tt 256
#define Ee 256
#define Uu 512
#define Vv 10000

// d_out staging layout (bytes). d_out = 512*10000*4 = 20,480,000 B (fp32 out).
// packB  @ 0           6,291,456  bf16 MFMA-packed [Wx;Wh], both dirs
// hbuf   @ 6,291,456   2,097,152  bf16 [parity][dir][B][U] ping-pong
// hidden @ 8,388,608     131,072  fp32 [512][64]
// cnt    @ 8,519,680       2,048  16 group counters, 128 B apart
// embB   @12,582,912   5,120,000  bf16 emb table
// Final fp32 softmax write covers everything; `hidden` overlaps only out rows
// 209..212 -> handled by the single-block tail pass. cnt/packB/hbuf/embB are
// dead by logits time.
#define PACKB_OFF 0
#define HBUF_OFF  6291456
#define HID_OFF   8388608
#define CNT_OFF   8519680
#define EMB_OFF   12582912

typedef __attribute__((ext_vector_type(8))) short short8;
typedef __attribute__((ext_vector_type(4))) float f32x4;

__device__ __forceinline__ float bf2f(ushort u) {
  union { unsigned int i; float f; } v; v.i = ((unsigned int)u) << 16; return v.f;
}
__device__ __forceinline__ ushort f2bf(float f) {
  union { float f; unsigned int i; } v; v.f = f;
  unsigned int x = v.i;
  return (ushort)((x + 0x7fffu + ((x >> 16) & 1u)) >> 16);  // RNE
}
__device__ __forceinline__ float fast_sigmoid(float x) {
  return 1.f / (1.f + __expf(-x));
}
__device__ __forceinline__ float fast_tanh(float x) {
  float t = __expf(-2.f * fabsf(x));
  float r = (1.f - t) / (1.f + t);
  return x >= 0.f ? r : -r;
}

// Coherent (L1/L2-bypassing, agent-scope) h accessors: h is the only buffer
// mutated cross-block during the persistent kernel, so no fences/invalidates
// are needed anywhere — emb/packB stay L2-warm.
__device__ __forceinline__ short8 load_h16(const ushort* p) {
  union { unsigned long long u[2]; short8 s; } v;
  v.u[0] = __hip_atomic_load((const unsigned long long*)p,     __ATOMIC_RELAXED, __HIP_MEMORY_SCOPE_AGENT);
  v.u[1] = __hip_atomic_load((const unsigned long long*)p + 1, __ATOMIC_RELAXED, __HIP_MEMORY_SCOPE_AGENT);
  return v.s;
}

// ---------------------------------------------------------------------------
// Zero hbuf (2 MB) + group counters (2 KB). 513 blocks.
// ---------------------------------------------------------------------------
__global__ __launch_bounds__(256) void init_zero(char* ob)
{
  if (blockIdx.x < 512) {
    uint4 z; z.x = 0; z.y = 0; z.z = 0; z.w = 0;
    ((uint4*)(ob + HBUF_OFF))[(size_t)blockIdx.x * 256 + threadIdx.x] = z;
  } else {
    uint2 z2; z2.x = 0; z2.y = 0;
    ((uint2*)(ob + CNT_OFF))[threadIdx.x] = z2;   // 256 * 8 B = 2048 B
  }
}

// ---------------------------------------------------------------------------
// emb fp32 -> bf16 table. 1250 blocks x 256 thr x 8 elems = 2,560,000.
// ---------------------------------------------------------------------------
__global__ __launch_bounds__(256) void conv_emb(const float* __restrict__ emb, char* ob)
{
  ushort* embB = (ushort*)(ob + EMB_OFF);
  size_t i = ((size_t)blockIdx.x * 256 + threadIdx.x) * 8;
  f32x4 f0 = *(const f32x4*)(emb + i);
  f32x4 f1 = *(const f32x4*)(emb + i + 4);
  short8 v;
  #pragma unroll
  for (int j = 0; j < 4; j++) {
    v[j]     = (short)f2bf(f0[j]);
    v[4 + j] = (short)f2bf(f1[j]);
  }
  *(short8*)(embB + i) = v;
}

// ---------------------------------------------------------------------------
// Pack W = concat(Wx[E][2048], Wh[U][2048]) (fp32) per dir into bf16 MFMA
// B-fragments: packB[((d*128 + ct)*24 + ks)*512 + lane*8 + j] =
//     bf16( W[k = ks*32 + (lane>>4)*8 + j][col = ct*16 + (lane&15)] )
// grid (4, 24, 2), block 256.
// ---------------------------------------------------------------------------
__global__ __launch_bounds__(256) void pack_weights(
    const float* __restrict__ Wx_fw, const float* __restrict__ Wh_fw,
    const float* __restrict__ Wx_bw, const float* __restrict__ Wh_bw,
    char* ob)
{
  __shared__ ushort tile[32][520];
  ushort* packB = (ushort*)(ob + PACKB_OFF);
  const int cq = blockIdx.x;
  const int ks = blockIdx.y;
  const int d  = blockIdx.z;
  const int tid = threadIdx.x;
  const float* Wx = d ? Wx_bw : Wx_fw;
  const float* Wh = d ? Wh_bw : Wh_fw;
  const int colbase = cq * 512;

  #pragma unroll
  for (int i = 0; i < 8; i++) {
    int chunk = tid + i * 256;
    int row = chunk >> 6;
    int cc = (chunk & 63) * 8;
    int k = ks * 32 + row;
    const float* src = (k < Ee) ? (Wx + (size_t)k * 2048 + colbase + cc)
                                : (Wh + (size_t)(k - Ee) * 2048 + colbase + cc);
    f32x4 f0 = *(const f32x4*)src;
    f32x4 f1 = *(const f32x4*)(src + 4);
    #pragma unroll
    for (int j = 0; j < 4; j++) {
      tile[row][cc + j]     = f2bf(f0[j]);
      tile[row][cc + 4 + j] = f2bf(f1[j]);
    }
  }
  __syncthreads();
  #pragma unroll
  for (int i = 0; i < 8; i++) {
    int chunk = tid + i * 256;
    int ctl = chunk >> 6;
    int lane = chunk & 63;
    int quad = lane >> 4, l15 = lane & 15;
    short8 v;
    #pragma unroll
    for (int jj = 0; jj < 8; jj++)
      v[jj] = (short)tile[quad * 8 + jj][ctl * 16 + l15];
    int ct = (colbase >> 4) + ctl;
    *(short8*)(packB + (((size_t)(d * 128 + ct) * 24 + ks) * 512) + lane * 8) = v;
  }
}

// ---------------------------------------------------------------------------
// Persistent bidirectional LSTM: all 256 steps in one launch.
// grid (32 utp, 8 bt, 2 d) = 512 blocks x 256 thr (4 waves) -> 2 blocks/CU
// (LDS 64 KB each; co-resident blocks from different sync groups interleave).
// Block tile: [64 batch rows x 16 u] x 4 gates; wave = 16 rows.
// Recurrent-part B (ks 8..23) lives in LDS for the whole kernel.
// c in registers (4 floats/lane). h exchanged via agent-scope atomics.
// Sync: per-(d,bt) group of 32 blocks, monotonic counter @CNT_OFF;
// poll = atomic LOAD (RMW polling serializes the line - round-6 lesson).
// ---------------------------------------------------------------------------
__global__ __launch_bounds__(256) void lstm_persistent(
    char* ob, const int* __restrict__ sent,
    const float* __restrict__ b_fw, const float* __restrict__ b_bw)
{
  __shared__ ushort ldsB[32768];   // 64 KB = [k8 0..15][q 0..3][512]
  const ushort* packB = (const ushort*)(ob + PACKB_OFF);
  const ushort* embB  = (const ushort*)(ob + EMB_OFF);
  ushort* hbuf = (ushort*)(ob + HBUF_OFF);

  const int utp = blockIdx.x;       // u-slice 0..31 (16 u each)
  const int bt  = blockIdx.y;       // batch slice 0..7 (64 rows)
  const int d   = blockIdx.z;
  unsigned int* cnt = (unsigned int*)(ob + CNT_OFF) + (d * 8 + bt) * 32;

  const int tid = threadIdx.x;
  const int w = tid >> 6, lane = tid & 63;
  const int l15 = lane & 15, quad = lane >> 4;
  const int mbase = bt * 64;
  const int mrow0 = mbase + w * 16;          // this wave's 16 rows
  const int u = utp * 16 + l15;

  // Stage recurrent-part B into LDS (once).
  for (int i = 0; i < 16; i++) {
    int c = tid + i * 256;                  // 0..4095 chunks of 16 B
    int lc = c & 63, qc = (c >> 6) & 3, k8 = c >> 8;
    const ushort* src = packB +
        ((size_t)(d * 128 + qc * 32 + utp) * 24 + 8 + k8) * 512 + lc * 8;
    *(short8*)&ldsB[(k8 * 4 + qc) * 512 + lc * 8] = *(const short8*)src;
  }

  const float* bias = d ? b_bw : b_fw;
  const float bi  = bias[u];
  const float bfv = bias[512 + u];
  const float bg  = bias[1024 + u];
  const float bo  = bias[1536 + u];

  const ushort* bembP[4];
  #pragma unroll
  for (int q = 0; q < 4; q++)
    bembP[q] = packB + ((size_t)(d * 128 + q * 32 + utp) * 24) * 512 + lane * 8;

  float creg[4];
  #pragma unroll
  for (int r = 0; r < 4; r++) creg[r] = 0.f;

  __syncthreads();   // LDS B ready

  for (int s = 0; s < Tt; s++) {
    const int t = d ? (Tt - 1 - s) : s;
    const ushort* hread  = hbuf + (size_t)((s & 1) * 2 + d) * Bb * Uu;
    ushort*       hwrite = hbuf + (size_t)((((s & 1) ^ 1) * 2) + d) * Bb * Uu;

    f32x4 acc[4];
    #pragma unroll
    for (int q = 0; q < 4; q++) acc[q] = (f32x4){0.f, 0.f, 0.f, 0.f};

    const int tok = sent[(mrow0 + l15) * Tt + t];
    const ushort* e0 = embB + (size_t)tok * Ee + quad * 8;

    // ---- emb part (K 0..255): independent of peers -> before the wait ----
    #pragma unroll
    for (int ks = 0; ks < 8; ks++) {
      short8 a0 = *(const short8*)(e0 + ks * 32);
      short8 bq0 = *(const short8*)(bembP[0] + ks * 512);
      short8 bq1 = *(const short8*)(bembP[1] + ks * 512);
      short8 bq2 = *(const short8*)(bembP[2] + ks * 512);
      short8 bq3 = *(const short8*)(bembP[3] + ks * 512);
      acc[0] = __builtin_amdgcn_mfma_f32_16x16x32_bf16(a0, bq0, acc[0], 0, 0, 0);
      acc[1] = __builtin_amdgcn_mfma_f32_16x16x32_bf16(a0, bq1, acc[1], 0, 0, 0);
      acc[2] = __builtin_amdgcn_mfma_f32_16x16x32_bf16(a0, bq2, acc[2], 0, 0, 0);
      acc[3] = __builtin_amdgcn_mfma_f32_16x16x32_bf16(a0, bq3, acc[3], 0, 0, 0);
    }

    // ---- wait: all 32 peer blocks finished step s-1 (h parity s&1 ready) --
    if (tid == 0) {
      const unsigned int target = 32u * (unsigned int)s;
      while (__hip_atomic_load(cnt, __ATOMIC_RELAXED,
                               __HIP_MEMORY_SCOPE_AGENT) < target)
        __builtin_amdgcn_s_sleep(1);
    }
    __syncthreads();

    // ---- recurrent part (K 256..767): B from LDS, A via coherent loads ---
    const ushort* h0 = hread + (size_t)(mrow0 + l15) * Uu + quad * 8;
    #pragma unroll
    for (int k8 = 0; k8 < 16; k8++) {
      short8 a0 = load_h16(h0 + k8 * 32);
      short8 bq0 = *(const short8*)&ldsB[(k8 * 4 + 0) * 512 + lane * 8];
      short8 bq1 = *(const short8*)&ldsB[(k8 * 4 + 1) * 512 + lane * 8];
      short8 bq2 = *(const short8*)&ldsB[(k8 * 4 + 2) * 512 + lane * 8];
      short8 bq3 = *(const short8*)&ldsB[(k8 * 4 + 3) * 512 + lane * 8];
      acc[0] = __builtin_amdgcn_mfma_f32_16x16x32_bf16(a0, bq0, acc[0], 0, 0, 0);
      acc[1] = __builtin_amdgcn_mfma_f32_16x16x32_bf16(a0, bq1, acc[1], 0, 0, 0);
      acc[2] = __builtin_amdgcn_mfma_f32_16x16x32_bf16(a0, bq2, acc[2], 0, 0, 0);
      acc[3] = __builtin_amdgcn_mfma_f32_16x16x32_bf16(a0, bq3, acc[3], 0, 0, 0);
    }

    // ---- pointwise + shfl-packed 8-byte coherent h stores ----------------
    // C/D layout: col = l15 (u), row = quad*4 + r. Lanes l15..l15+3 within a
    // quad hold the SAME row for adjacent u -> pack 4 bf16 into 8 B.
    #pragma unroll
    for (int r = 0; r < 4; r++) {
      float iv = fast_sigmoid(acc[0][r] + bi);
      float fv = fast_sigmoid(acc[1][r] + bfv);
      float gv = fast_tanh(acc[2][r] + bg);
      float ov = fast_sigmoid(acc[3][r] + bo);
      float cn = fv * creg[r] + iv * gv;
      creg[r] = cn;
      unsigned int x = f2bf(ov * fast_tanh(cn));
      unsigned int y = (unsigned int)__shfl_xor((int)x, 1);
      unsigned int w01 = x | (y << 16);                 // valid on even l15
      unsigned int w23 = (unsigned int)__shfl_xor((int)w01, 2); // from l15+2
      if ((l15 & 3) == 0) {
        int m = mrow0 + quad * 4 + r;
        unsigned long long v8 = ((unsigned long long)w23 << 32) | w01;
        __hip_atomic_store(
            (unsigned long long*)(hwrite + (size_t)m * Uu + utp * 16 + l15),
            v8, __ATOMIC_RELAXED, __HIP_MEMORY_SCOPE_AGENT);
      }
    }

    // ---- arrive: syncthreads drains vmcnt(0) in every thread first -------
    __syncthreads();
    if (tid == 0)
      __hip_atomic_fetch_add(cnt, 1u, __ATOMIC_RELAXED, __HIP_MEMORY_SCOPE_AGENT);
  }
}

// ---------------------------------------------------------------------------
// hidden = relu([h_fw, h_bw] @ W1 + b1) -> fp32 @ HID_OFF.
// grid 128, block 256: 4 rows x 64 cols.
// ---------------------------------------------------------------------------
__global__ __launch_bounds__(256) void hidden_kernel(
    char* ob, const float* __restrict__ W1, const float* __restrict__ b1)
{
  const ushort* hbuf = (const ushort*)(ob + HBUF_OFF);   // parity 0 = final h
  float* hidden = (float*)(ob + HID_OFF);
  int m = blockIdx.x * 4 + (threadIdx.x >> 6);
  int col = threadIdx.x & 63;
  const ushort* hf = hbuf + (size_t)m * Uu;
  const ushort* hb = hbuf + (size_t)(Bb + m) * Uu;
  float acc = b1[col];
  for (int k = 0; k < 512; k++) acc += bf2f(hf[k]) * W1[k * 64 + col];
  for (int k = 0; k < 512; k++) acc += bf2f(hb[k]) * W1[(512 + k) * 64 + col];
  hidden[(size_t)m * 64 + col] = fmaxf(acc, 0.f);
}

// ---------------------------------------------------------------------------
// Softmax row body: given hs[64] in LDS, compute + store fp32 probs for row m.
// ---------------------------------------------------------------------------
__device__ __forceinline__ void softmax_row(
    const float* hs, const float* __restrict__ W2, const float* __restrict__ b2,
    float* out, int m, float* red)
{
  const int tid = threadIdx.x;
  float lg[40];
  float mx = -1e30f;
  #pragma unroll 4
  for (int i = 0; i < 40; i++) {
    int c = tid + i * 256;
    float a = -1e30f;
    if (c < Vv) {
      a = b2[c];
      for (int k = 0; k < 64; k++) a += hs[k] * W2[(size_t)k * Vv + c];
    }
    lg[i] = a;
    mx = fmaxf(mx, a);
  }
  red[tid] = mx; __syncthreads();
  for (int off = 128; off > 0; off >>= 1) {
    if (tid < off) red[tid] = fmaxf(red[tid], red[tid + off]);
    __syncthreads();
  }
  mx = red[0];
  __syncthreads();

  float sum = 0.f;
  #pragma unroll 4
  for (int i = 0; i < 40; i++) {
    int c = tid + i * 256;
    if (c < Vv) { lg[i] = __expf(lg[i] - mx); sum += lg[i]; }
  }
  red[tid] = sum; __syncthreads();
  for (int off = 128; off > 0; off >>= 1) {
    if (tid < off) red[tid] += red[tid + off];
    __syncthreads();
  }
  float inv = 1.f / red[0];
  __syncthreads();
  #pragma unroll 4
  for (int i = 0; i < 40; i++) {
    int c = tid + i * 256;
    if (c < Vv) out[(size_t)m * Vv + c] = lg[i] * inv;
  }
}

// ---------------------------------------------------------------------------
// Pass A: all rows except 209..212 (those overlap the hidden staging region).
// ---------------------------------------------------------------------------
__global__ __launch_bounds__(256) void logits_main(
    char* ob, const float* __restrict__ W2, const float* __restrict__ b2)
{
  __shared__ float hs[64];
  __shared__ float red[256];
  const float* hidden = (const float*)(ob + HID_OFF);
  float* out = (float*)ob;
  int bx = blockIdx.x;
  int m = (bx < 209) ? bx : (bx + 4);
  if (threadIdx.x < 64) hs[threadIdx.x] = hidden[(size_t)m * 64 + threadIdx.x];
  __syncthreads();
  softmax_row(hs, W2, b2, out, m, red);
}

// ---------------------------------------------------------------------------
// Pass B: rows 209..212, ONE block; preload all 4 hidden rows before storing.
// ---------------------------------------------------------------------------
__global__ __launch_bounds__(256) void logits_tail(
    char* ob, const float* __restrict__ W2, const float* __restrict__ b2)
{
  __shared__ float hs4[4][64];
  __shared__ float red[256];
  const float* hidden = (const float*)(ob + HID_OFF);
  float* out = (float*)ob;
  {
    int r = threadIdx.x >> 6, col = threadIdx.x & 63;
    hs4[r][col] = hidden[(size_t)(209 + r) * 64 + col];
  }
  __syncthreads();
  for (int r = 0; r < 4; r++) {
    softmax_row(hs4[r], W2, b2, out, 209 + r, red);
    __syncthreads();
  }
}

extern "C" void kernel_launch(void* const* d_in, const int* in_sizes, int n_in,
                              void* d_out, int out_size, void* d_ws, size_t ws_size,
                              hipStream_t stream)
{
  const int*   sent  = (const int*)d_in[0];
  const float* emb   = (const float*)d_in[1];
  const float* Wx_fw = (const float*)d_in[2];
  const float* Wh_fw = (const float*)d_in[3];
  const float* b_fw  = (const float*)d_in[4];
  const float* Wx_bw = (const float*)d_in[5];
  const float* Wh_bw = (const float*)d_in[6];
  const float* b_bw  = (const float*)d_in[7];
  const float* W1    = (const float*)d_in[8];
  const float* b1    = (const float*)d_in[9];
  const float* W2    = (const float*)d_in[10];
  const float* b2    = (const float*)d_in[11];
  char* ob = (char*)d_out;
  (void)d_ws; (void)ws_size; (void)in_sizes; (void)n_in; (void)out_size;

  init_zero<<<513, 256, 0, stream>>>(ob);
  pack_weights<<<dim3(4, 24, 2), 256, 0, stream>>>(Wx_fw, Wh_fw, Wx_bw, Wh_bw, ob);
  conv_emb<<<1250, 256, 0, stream>>>(emb, ob);

  lstm_persistent<<<dim3(32, 8, 2), 256, 0, stream>>>(ob, sent, b_fw, b_bw);

  hidden_kernel<<<128, 256, 0, stream>>>(ob, W1, b1);
  logits_main<<<508, 256, 0, stream>>>(ob, W2, b2);
  logits_tail<<<1,   256, 0, stream>>>(ob, W2, b2);
}